// Round 1
// baseline (31297.415 us; speedup 1.0000x reference)
//
#include <hip/hip_runtime.h>

#define B_ROWS 16384
#define S_ROWS 12800
#define DIM    128
#define TILE   64

static constexpr float INV_T = 1.0f / 0.07f;  // TEMPERATURE = 0.07

// Sortable packing: larger float -> larger key; ties -> smaller col wins (matches jnp.argmax first-max).
__device__ __forceinline__ unsigned long long packMax(float v, int col) {
  unsigned int b = __float_as_uint(v);
  unsigned int key = (b & 0x80000000u) ? ~b : (b | 0x80000000u);
  return ((unsigned long long)key << 32) | (unsigned long long)(0xFFFFFFFFu - (unsigned int)col);
}

__global__ __launch_bounds__(256) void init_ws(float* __restrict__ centsum,
                                               unsigned long long* __restrict__ gpacked,
                                               float* __restrict__ jsum) {
  int i = blockIdx.x * 256 + threadIdx.x;
  if (i < S_ROWS) centsum[i] = 0.f;
  if (i < B_ROWS) gpacked[i] = 0ull;  // any finite packed value > 0
  if (i == 0) jsum[0] = 0.f;
}

// One wave per centroid row: c = cent / max(||cent||, 1e-12)
__global__ __launch_bounds__(64) void normalize_centroids(const float* __restrict__ cent,
                                                          float* __restrict__ cnorm) {
  int row = blockIdx.x;
  int lane = threadIdx.x;
  float2 v = ((const float2*)(cent + (size_t)row * DIM))[lane];
  float ss = v.x * v.x + v.y * v.y;
  #pragma unroll
  for (int m = 32; m; m >>= 1) ss += __shfl_xor(ss, m, 64);
  float n = fmaxf(sqrtf(ss), 1e-12f);
  float2 o; o.x = v.x / n; o.y = v.y / n;
  ((float2*)(cnorm + (size_t)row * DIM))[lane] = o;
}

// 64x64 tile, 256 threads, 4x4 acc per thread, K=128 in two 64-wide halves.
// MODE 0: centsum[row] += sum_cols exp(dot*invT)   (A=B=cnorm; symmetric => rowsum == colsum)
// MODE 1: gpacked[row]  = max/argmax over cols of dot (A=features, B=cnorm)
template <int MODE>
__global__ __launch_bounds__(256) void tile_kernel(const float* __restrict__ Amat,
                                                   const float* __restrict__ Bmat,
                                                   float* __restrict__ centsum,
                                                   unsigned long long* __restrict__ gpacked) {
  __shared__ float As[TILE][68];  // row stride 68 floats: float4-aligned, read-conflict-free
  __shared__ float Bs[TILE][68];
  const int row0 = blockIdx.y * TILE;
  const int col0 = blockIdx.x * TILE;
  const int t  = threadIdx.x;
  const int tx = t & 15;   // col group: cols tx + 16*i
  const int ty = t >> 4;   // row group: rows ty + 16*j

  float acc[4][4] = {};

  #pragma unroll
  for (int kh = 0; kh < 2; ++kh) {
    if (kh) __syncthreads();
    // stage 64 rows x 64 k of each operand (coalesced float4 loads)
    #pragma unroll
    for (int i = 0; i < 4; ++i) {
      int idx = t + 256 * i;
      int m  = idx >> 4;    // 0..63
      int c4 = idx & 15;    // 0..15
      const float4 ga = *(const float4*)(Amat + (size_t)(row0 + m) * DIM + kh * 64 + c4 * 4);
      const float4 gb = *(const float4*)(Bmat + (size_t)(col0 + m) * DIM + kh * 64 + c4 * 4);
      *(float4*)&As[m][c4 * 4] = ga;
      *(float4*)&Bs[m][c4 * 4] = gb;
    }
    __syncthreads();
    #pragma unroll
    for (int k4 = 0; k4 < 16; ++k4) {
      float4 a[4], b[4];
      #pragma unroll
      for (int j = 0; j < 4; ++j) a[j] = *(const float4*)&As[ty + 16 * j][k4 * 4];
      #pragma unroll
      for (int i = 0; i < 4; ++i) b[i] = *(const float4*)&Bs[tx + 16 * i][k4 * 4];
      #pragma unroll
      for (int j = 0; j < 4; ++j)
        #pragma unroll
        for (int i = 0; i < 4; ++i)
          acc[j][i] += a[j].x * b[i].x + a[j].y * b[i].y + a[j].z * b[i].z + a[j].w * b[i].w;
    }
  }

  if (MODE == 0) {
    #pragma unroll
    for (int j = 0; j < 4; ++j) {
      float s = 0.f;
      #pragma unroll
      for (int i = 0; i < 4; ++i) s += expf(acc[j][i] * INV_T);
      #pragma unroll
      for (int msk = 1; msk < 16; msk <<= 1) s += __shfl_xor(s, msk, 64);
      if (tx == 0) atomicAdd(&centsum[row0 + ty + 16 * j], s);
    }
  } else {
    #pragma unroll
    for (int j = 0; j < 4; ++j) {
      float best = acc[j][0];
      int bc = col0 + tx;
      #pragma unroll
      for (int i = 1; i < 4; ++i) {
        int c = col0 + tx + 16 * i;
        if (acc[j][i] > best) { best = acc[j][i]; bc = c; }
      }
      unsigned long long pk = packMax(best, bc);
      #pragma unroll
      for (int msk = 1; msk < 16; msk <<= 1) {
        unsigned long long o = __shfl_xor(pk, msk, 64);
        if (o > pk) pk = o;
      }
      if (tx == 0) atomicMax(&gpacked[row0 + ty + 16 * j], pk);
    }
  }
}

__global__ __launch_bounds__(256) void finalize_rows(const unsigned long long* __restrict__ gpacked,
                                                     const float* __restrict__ centsum,
                                                     float* __restrict__ jsum) {
  __shared__ float sdata[4];
  int b = blockIdx.x * 256 + threadIdx.x;
  unsigned long long pk = gpacked[b];
  unsigned int key = (unsigned int)(pk >> 32);
  unsigned int col = 0xFFFFFFFFu - (unsigned int)(pk & 0xFFFFFFFFu);
  unsigned int bits = (key & 0x80000000u) ? (key & 0x7FFFFFFFu) : ~key;
  float m = __uint_as_float(bits);
  float p = expf(m * INV_T);                 // exp monotone: max(exp(x)) == exp(max(x))
  float J = logf(p) - logf(p + centsum[col]); // BALANCE = 1.0
  #pragma unroll
  for (int msk = 1; msk < 64; msk <<= 1) J += __shfl_xor(J, msk, 64);
  int lane = threadIdx.x & 63, w = threadIdx.x >> 6;
  if (lane == 0) sdata[w] = J;
  __syncthreads();
  if (threadIdx.x == 0) atomicAdd(jsum, sdata[0] + sdata[1] + sdata[2] + sdata[3]);
}

__global__ void write_out(const float* __restrict__ jsum, float* __restrict__ out) {
  out[0] = -(jsum[0] / (float)B_ROWS);
}

extern "C" void kernel_launch(void* const* d_in, const int* in_sizes, int n_in,
                              void* d_out, int out_size, void* d_ws, size_t ws_size,
                              hipStream_t stream) {
  const float* features  = (const float*)d_in[0];
  const float* centroids = (const float*)d_in[1];
  float* out = (float*)d_out;

  // ws layout: cnorm[S*D] f32 | centsum[S] f32 | gpacked[B] u64 (8B-aligned) | jsum[1] f32  (~6.74 MB)
  float* cnorm   = (float*)d_ws;
  float* centsum = cnorm + (size_t)S_ROWS * DIM;
  unsigned long long* gpacked = (unsigned long long*)(centsum + S_ROWS);
  float* jsum = (float*)(gpacked + B_ROWS);

  init_ws<<<dim3(64), dim3(256), 0, stream>>>(centsum, gpacked, jsum);
  normalize_centroids<<<dim3(S_ROWS), dim3(64), 0, stream>>>(centroids, cnorm);
  tile_kernel<0><<<dim3(S_ROWS / TILE, S_ROWS / TILE), dim3(256), 0, stream>>>(cnorm, cnorm, centsum, gpacked);
  tile_kernel<1><<<dim3(S_ROWS / TILE, B_ROWS / TILE), dim3(256), 0, stream>>>(features, cnorm, centsum, gpacked);
  finalize_rows<<<dim3(B_ROWS / 256), dim3(256), 0, stream>>>(gpacked, centsum, jsum);
  write_out<<<dim3(1), dim3(1), 0, stream>>>(jsum, out);
}

// Round 2
// 450.479 us; speedup vs baseline: 69.4759x; 69.4759x over previous
//
#include <hip/hip_runtime.h>

#define B_ROWS 16384
#define S_ROWS 12800
#define DIM    128

static constexpr float INV_T = 1.0f / 0.07f;  // TEMPERATURE = 0.07

typedef __attribute__((ext_vector_type(8))) short short8;
typedef __attribute__((ext_vector_type(4))) float f32x4;

// f32 -> bf16 round-to-nearest-even
__device__ __forceinline__ unsigned short f2bf(float f) {
  unsigned int u = __float_as_uint(f);
  unsigned int r = (u + 0x7FFFu + ((u >> 16) & 1u)) >> 16;
  return (unsigned short)r;
}

// Sortable packing: larger float -> larger key; ties -> smaller col wins (matches jnp.argmax).
__device__ __forceinline__ unsigned long long packMax(float v, int col) {
  unsigned int b = __float_as_uint(v);
  unsigned int key = (b & 0x80000000u) ? ~b : (b | 0x80000000u);
  return ((unsigned long long)key << 32) | (unsigned long long)(0xFFFFFFFFu - (unsigned int)col);
}

// async global->LDS, 16B per lane, wave-uniform LDS base (HW adds lane*16)
__device__ __forceinline__ void gld16(const unsigned short* g, unsigned short* l) {
  __builtin_amdgcn_global_load_lds(
      (const __attribute__((address_space(1))) unsigned int*)g,
      (__attribute__((address_space(3))) unsigned int*)l,
      16, 0, 0);
}

__global__ __launch_bounds__(256) void init_ws(float* __restrict__ centsum,
                                               unsigned long long* __restrict__ gpacked,
                                               float* __restrict__ jsum) {
  int i = blockIdx.x * 256 + threadIdx.x;
  if (i < S_ROWS) centsum[i] = 0.f;
  if (i < B_ROWS) gpacked[i] = 0ull;
  if (i == 0) jsum[0] = 0.f;
}

// 4 rows per block (1 wave each): cbf[row] = bf16( cent[row] / max(||cent[row]||, 1e-12) )
__global__ __launch_bounds__(256) void normalize_centroids_bf16(const float* __restrict__ cent,
                                                                unsigned short* __restrict__ cbf) {
  int row  = blockIdx.x * 4 + (threadIdx.x >> 6);
  int lane = threadIdx.x & 63;
  float2 v = ((const float2*)(cent + (size_t)row * DIM))[lane];
  float ss = v.x * v.x + v.y * v.y;
  #pragma unroll
  for (int m = 32; m; m >>= 1) ss += __shfl_xor(ss, m, 64);
  float inv = 1.0f / fmaxf(sqrtf(ss), 1e-12f);
  unsigned short h0 = f2bf(v.x * inv), h1 = f2bf(v.y * inv);
  unsigned int packed = (unsigned int)h0 | ((unsigned int)h1 << 16);
  ((unsigned int*)(cbf + (size_t)row * DIM))[lane] = packed;
}

// 128x128 output tile, 256 threads (4 waves, 64x64 each), K=128 staged once.
// LDS layout: [128 rows][16 chunks of 16B], chunk XOR-swizzled by (row&7).
// MODE 0: centsum[row] += sum_cols exp(dot*INV_T)   (A=B=cnorm_bf16, both via global_load_lds)
// MODE 1: gpacked[row]  = max/argmax over cols      (A=features f32 reg-staged, B=cnorm_bf16)
template <int MODE>
__global__ __launch_bounds__(256, 2) void tile_mfma(const float* __restrict__ Af32,
                                                    const unsigned short* __restrict__ Abf,
                                                    const unsigned short* __restrict__ Bbf,
                                                    float* __restrict__ centsum,
                                                    unsigned long long* __restrict__ gpacked) {
  __shared__ unsigned short As[128 * 128];  // 32 KB
  __shared__ unsigned short Bs[128 * 128];  // 32 KB

  const int t    = threadIdx.x;
  const int w    = t >> 6;
  const int lane = t & 63;
  const int row0 = blockIdx.y * 128;
  const int col0 = blockIdx.x * 128;

  // ---- stage B (and A for MODE 0) via global_load_lds, pre-swizzled global source ----
  #pragma unroll
  for (int i = 0; i < 8; ++i) {
    int rb = w * 32 + i * 4;           // 4 rows per issue, wave-uniform LDS base
    int r  = rb + (lane >> 4);         // this lane's row (0..127 local)
    int ch = (lane & 15) ^ (r & 7);    // inverse-swizzled source chunk
    gld16(Bbf + (size_t)(col0 + r) * DIM + ch * 8, &Bs[rb * 128]);
    if (MODE == 0) gld16(Abf + (size_t)(row0 + r) * DIM + ch * 8, &As[rb * 128]);
  }
  if (MODE == 1) {
    // reg-stage features f32 -> bf16, swizzled ds_write_b128
    #pragma unroll
    for (int i = 0; i < 8; ++i) {
      int q = i * 256 + t;
      int r = q >> 4, c = q & 15;
      const float* src = Af32 + (size_t)(row0 + r) * DIM + c * 8;
      float4 v0 = *(const float4*)src;
      float4 v1 = *(const float4*)(src + 4);
      short8 h;
      h[0] = (short)f2bf(v0.x); h[1] = (short)f2bf(v0.y);
      h[2] = (short)f2bf(v0.z); h[3] = (short)f2bf(v0.w);
      h[4] = (short)f2bf(v1.x); h[5] = (short)f2bf(v1.y);
      h[6] = (short)f2bf(v1.z); h[7] = (short)f2bf(v1.w);
      *(short8*)&As[(size_t)r * 128 + (size_t)((c ^ (r & 7)) * 8)] = h;
    }
  }
  asm volatile("s_waitcnt vmcnt(0)" ::: "memory");
  __syncthreads();

  // ---- MFMA: wave quadrant (wr,wc), 4x4 fragments of 16x16, K=4 steps of 32 ----
  const int wr = w >> 1, wc = w & 1;
  const int lg = lane >> 4;   // k-group 0..3
  const int li = lane & 15;   // row/col within fragment

  f32x4 zero = {0.f, 0.f, 0.f, 0.f};
  f32x4 acc[4][4];
  #pragma unroll
  for (int m = 0; m < 4; ++m)
    #pragma unroll
    for (int n = 0; n < 4; ++n) acc[m][n] = zero;

  #pragma unroll
  for (int ks = 0; ks < 4; ++ks) {
    short8 a[4], b[4];
    #pragma unroll
    for (int m = 0; m < 4; ++m) {
      int r  = wr * 64 + m * 16 + li;
      int ch = (ks * 4 + lg) ^ (r & 7);
      a[m] = *(const short8*)&As[r * 128 + ch * 8];
    }
    #pragma unroll
    for (int n = 0; n < 4; ++n) {
      int c  = wc * 64 + n * 16 + li;
      int ch = (ks * 4 + lg) ^ (c & 7);
      b[n] = *(const short8*)&Bs[c * 128 + ch * 8];
    }
    #pragma unroll
    for (int m = 0; m < 4; ++m)
      #pragma unroll
      for (int n = 0; n < 4; ++n)
        acc[m][n] = __builtin_amdgcn_mfma_f32_16x16x32_bf16(a[m], b[n], acc[m][n], 0, 0, 0);
  }

  // ---- epilogue ----  C/D layout: col = li, row = lg*4 + reg  [m89]
  if (MODE == 0) {
    #pragma unroll
    for (int m = 0; m < 4; ++m) {
      float s0 = 0.f, s1 = 0.f, s2 = 0.f, s3 = 0.f;
      #pragma unroll
      for (int n = 0; n < 4; ++n) {
        s0 += __expf(acc[m][n][0] * INV_T);
        s1 += __expf(acc[m][n][1] * INV_T);
        s2 += __expf(acc[m][n][2] * INV_T);
        s3 += __expf(acc[m][n][3] * INV_T);
      }
      #pragma unroll
      for (int msk = 1; msk < 16; msk <<= 1) {
        s0 += __shfl_xor(s0, msk, 64);
        s1 += __shfl_xor(s1, msk, 64);
        s2 += __shfl_xor(s2, msk, 64);
        s3 += __shfl_xor(s3, msk, 64);
      }
      if (li == 0) {
        int rbase = row0 + wr * 64 + m * 16 + lg * 4;
        atomicAdd(&centsum[rbase + 0], s0);
        atomicAdd(&centsum[rbase + 1], s1);
        atomicAdd(&centsum[rbase + 2], s2);
        atomicAdd(&centsum[rbase + 3], s3);
      }
    }
  } else {
    #pragma unroll
    for (int m = 0; m < 4; ++m) {
      #pragma unroll
      for (int j = 0; j < 4; ++j) {
        float best = acc[m][0][j];
        int   bc   = col0 + wc * 64 + li;
        #pragma unroll
        for (int n = 1; n < 4; ++n) {
          int   c = col0 + wc * 64 + n * 16 + li;
          float v = acc[m][n][j];
          if (v > best) { best = v; bc = c; }
        }
        unsigned long long pk = packMax(best, bc);
        #pragma unroll
        for (int msk = 1; msk < 16; msk <<= 1) {
          unsigned long long o = __shfl_xor(pk, msk, 64);
          if (o > pk) pk = o;
        }
        if (li == 0) atomicMax(&gpacked[row0 + wr * 64 + m * 16 + lg * 4 + j], pk);
      }
    }
  }
}

__global__ __launch_bounds__(256) void finalize_rows(const unsigned long long* __restrict__ gpacked,
                                                     const float* __restrict__ centsum,
                                                     float* __restrict__ jsum) {
  __shared__ float sdata[4];
  int b = blockIdx.x * 256 + threadIdx.x;
  unsigned long long pk = gpacked[b];
  unsigned int key = (unsigned int)(pk >> 32);
  unsigned int col = 0xFFFFFFFFu - (unsigned int)(pk & 0xFFFFFFFFu);
  unsigned int bits = (key & 0x80000000u) ? (key & 0x7FFFFFFFu) : ~key;
  float m = __uint_as_float(bits);
  float p = expf(m * INV_T);
  float J = logf(p) - logf(p + centsum[col]);  // BALANCE = 1.0
  #pragma unroll
  for (int msk = 1; msk < 64; msk <<= 1) J += __shfl_xor(J, msk, 64);
  int lane = threadIdx.x & 63, wv = threadIdx.x >> 6;
  if (lane == 0) sdata[wv] = J;
  __syncthreads();
  if (threadIdx.x == 0) atomicAdd(jsum, sdata[0] + sdata[1] + sdata[2] + sdata[3]);
}

__global__ void write_out(const float* __restrict__ jsum, float* __restrict__ out) {
  out[0] = -(jsum[0] / (float)B_ROWS);
}

extern "C" void kernel_launch(void* const* d_in, const int* in_sizes, int n_in,
                              void* d_out, int out_size, void* d_ws, size_t ws_size,
                              hipStream_t stream) {
  const float* features  = (const float*)d_in[0];
  const float* centroids = (const float*)d_in[1];
  float* out = (float*)d_out;

  // ws layout: cnorm_bf16[S*D] u16 | centsum[S] f32 | gpacked[B] u64 | jsum f32   (~3.5 MB)
  unsigned short* cbf = (unsigned short*)d_ws;
  float* centsum = (float*)(cbf + (size_t)S_ROWS * DIM);
  unsigned long long* gpacked = (unsigned long long*)(centsum + S_ROWS);
  float* jsum = (float*)(gpacked + B_ROWS);

  init_ws<<<dim3(64), dim3(256), 0, stream>>>(centsum, gpacked, jsum);
  normalize_centroids_bf16<<<dim3(S_ROWS / 4), dim3(256), 0, stream>>>(centroids, cbf);
  tile_mfma<0><<<dim3(S_ROWS / 128, S_ROWS / 128), dim3(256), 0, stream>>>(nullptr, cbf, cbf, centsum, gpacked);
  tile_mfma<1><<<dim3(S_ROWS / 128, B_ROWS / 128), dim3(256), 0, stream>>>(features, nullptr, cbf, centsum, gpacked);
  finalize_rows<<<dim3(B_ROWS / 256), dim3(256), 0, stream>>>(gpacked, centsum, jsum);
  write_out<<<dim3(1), dim3(1), 0, stream>>>(jsum, out);
}

// Round 3
// 128.182 us; speedup vs baseline: 244.1633x; 3.5144x over previous
//
#include <hip/hip_runtime.h>

#define B_ROWS 16384
#define S_ROWS 12800
#define DIM    128

static constexpr float INV_T = 1.0f / 0.07f;  // TEMPERATURE = 0.07

typedef __attribute__((ext_vector_type(8))) short short8;
typedef __attribute__((ext_vector_type(4))) float f32x4;

// f32 -> bf16 round-to-nearest-even
__device__ __forceinline__ unsigned short f2bf(float f) {
  unsigned int u = __float_as_uint(f);
  unsigned int r = (u + 0x7FFFu + ((u >> 16) & 1u)) >> 16;
  return (unsigned short)r;
}

// Sortable packing: larger float -> larger key; ties -> smaller col wins (matches jnp.argmax).
__device__ __forceinline__ unsigned long long packMax(float v, int col) {
  unsigned int b = __float_as_uint(v);
  unsigned int key = (b & 0x80000000u) ? ~b : (b | 0x80000000u);
  return ((unsigned long long)key << 32) | (unsigned long long)(0xFFFFFFFFu - (unsigned int)col);
}

// async global->LDS, 16B per lane, wave-uniform LDS base (HW adds lane*16)
__device__ __forceinline__ void gld16(const unsigned short* g, unsigned short* l) {
  __builtin_amdgcn_global_load_lds(
      (const __attribute__((address_space(1))) unsigned int*)g,
      (__attribute__((address_space(3))) unsigned int*)l,
      16, 0, 0);
}

__global__ __launch_bounds__(256) void init_ws(float* __restrict__ centsum,
                                               unsigned long long* __restrict__ gpacked,
                                               float* __restrict__ jsum) {
  int i = blockIdx.x * 256 + threadIdx.x;
  if (i < S_ROWS) centsum[i] = 0.f;
  if (i < B_ROWS) gpacked[i] = 0ull;
  if (i == 0) jsum[0] = 0.f;
}

// 4 rows per block (1 wave each): cbf[row] = bf16( cent[row] / max(||cent[row]||, 1e-12) )
__global__ __launch_bounds__(256) void normalize_centroids_bf16(const float* __restrict__ cent,
                                                                unsigned short* __restrict__ cbf) {
  int row  = blockIdx.x * 4 + (threadIdx.x >> 6);
  int lane = threadIdx.x & 63;
  float2 v = ((const float2*)(cent + (size_t)row * DIM))[lane];
  float ss = v.x * v.x + v.y * v.y;
  #pragma unroll
  for (int m = 32; m; m >>= 1) ss += __shfl_xor(ss, m, 64);
  float inv = 1.0f / fmaxf(sqrtf(ss), 1e-12f);
  unsigned short h0 = f2bf(v.x * inv), h1 = f2bf(v.y * inv);
  unsigned int packed = (unsigned int)h0 | ((unsigned int)h1 << 16);
  ((unsigned int*)(cbf + (size_t)row * DIM))[lane] = packed;
}

// Strip-mined GEMM: block = 128 rows x (NT tiles of 128 cols), K=128 held fully.
// 4 waves, wave tile 64x64. A kept in registers for the whole strip; B double-buffered
// in LDS with 2-phase prefetch. Running per-lane epilogue state; one reduce per strip.
// MODE 0: centsum[row] += sum_cols exp(dot*INV_T)    (A rows = cbf, NT=20, chunks=5)
// MODE 1: gpacked[row]  = max/argmax over cols       (A rows = features, NT=25, chunks=4)
template <int MODE>
__global__ __launch_bounds__(256, 2) void strip_mfma(const float* __restrict__ Af32,
                                                     const unsigned short* __restrict__ Abf,
                                                     const unsigned short* __restrict__ Bbf,
                                                     float* __restrict__ centsum,
                                                     unsigned long long* __restrict__ gpacked) {
  constexpr int NT = (MODE == 0) ? 20 : 25;
  __shared__ unsigned short Bs[2][128 * 128];  // 2 x 32 KB

  const int t     = threadIdx.x;
  const int w     = t >> 6;
  const int lane  = t & 63;
  const int row0  = blockIdx.y * 128;
  const int tile0 = blockIdx.x * NT;

  const int wr = w >> 1, wc = w & 1;
  const int lg = lane >> 4, li = lane & 15;

  // ---- prologue: stage A tile (128 rows x 128 K bf16) into Bs[0], swizzled ----
  if (MODE == 0) {
    #pragma unroll
    for (int i = 0; i < 8; ++i) {
      int rb = w * 32 + i * 4;
      int r  = rb + (lane >> 4);
      int ch = (lane & 15) ^ (r & 7);
      gld16(Abf + (size_t)(row0 + r) * DIM + ch * 8, &Bs[0][rb * 128]);
    }
    asm volatile("s_waitcnt vmcnt(0)" ::: "memory");
  } else {
    #pragma unroll
    for (int i = 0; i < 8; ++i) {
      int q = i * 256 + t;
      int r = q >> 4, c = q & 15;
      const float* src = Af32 + (size_t)(row0 + r) * DIM + c * 8;
      float4 v0 = *(const float4*)src;
      float4 v1 = *(const float4*)(src + 4);
      short8 h;
      h[0] = (short)f2bf(v0.x); h[1] = (short)f2bf(v0.y);
      h[2] = (short)f2bf(v0.z); h[3] = (short)f2bf(v0.w);
      h[4] = (short)f2bf(v1.x); h[5] = (short)f2bf(v1.y);
      h[6] = (short)f2bf(v1.z); h[7] = (short)f2bf(v1.w);
      *(short8*)&Bs[0][r * 128 + (c ^ (r & 7)) * 8] = h;
    }
  }
  __syncthreads();

  // ---- A fragments to registers (64 VGPR), strip-resident ----
  short8 a[4][4];
  #pragma unroll
  for (int m = 0; m < 4; ++m)
    #pragma unroll
    for (int ks = 0; ks < 4; ++ks) {
      int r  = wr * 64 + m * 16 + li;
      int ch = (ks * 4 + lg) ^ (r & 7);
      a[m][ks] = *(const short8*)&Bs[0][r * 128 + ch * 8];
    }
  __syncthreads();  // all A reads done before Bs[0] is reused for B tiles

  // ---- running epilogue state ----
  float rs[4][4];            // MODE 0: row-sums
  float bv[4][4];            // MODE 1: best value
  int   bc[4][4];            // MODE 1: best col
  #pragma unroll
  for (int m = 0; m < 4; ++m)
    #pragma unroll
    for (int j = 0; j < 4; ++j) { rs[m][j] = 0.f; bv[m][j] = -3.0e38f; bc[m][j] = 0; }

  // ---- pre-stage B tile 0 ----
  {
    int colbase = tile0 * 128;
    #pragma unroll
    for (int i = 0; i < 8; ++i) {
      int rb = w * 32 + i * 4;
      int r  = rb + (lane >> 4);
      int ch = (lane & 15) ^ (r & 7);
      gld16(Bbf + (size_t)(colbase + r) * DIM + ch * 8, &Bs[0][rb * 128]);
    }
  }
  __syncthreads();

  // ---- main strip loop: prefetch(t+1) || compute(t) ----
  for (int tt = 0; tt < NT; ++tt) {
    if (tt + 1 < NT) {
      int colbase = (tile0 + tt + 1) * 128;
      unsigned short* dst = &Bs[(tt + 1) & 1][0];
      #pragma unroll
      for (int i = 0; i < 8; ++i) {
        int rb = w * 32 + i * 4;
        int r  = rb + (lane >> 4);
        int ch = (lane & 15) ^ (r & 7);
        gld16(Bbf + (size_t)(colbase + r) * DIM + ch * 8, dst + rb * 128);
      }
    }
    const unsigned short* cur = &Bs[tt & 1][0];
    const int col0 = (tile0 + tt) * 128;

    f32x4 acc[4][4];
    #pragma unroll
    for (int m = 0; m < 4; ++m)
      #pragma unroll
      for (int n = 0; n < 4; ++n) acc[m][n] = (f32x4){0.f, 0.f, 0.f, 0.f};

    #pragma unroll
    for (int ks = 0; ks < 4; ++ks) {
      short8 b[4];
      #pragma unroll
      for (int n = 0; n < 4; ++n) {
        int c  = wc * 64 + n * 16 + li;
        int ch = (ks * 4 + lg) ^ (c & 7);
        b[n] = *(const short8*)&cur[c * 128 + ch * 8];
      }
      #pragma unroll
      for (int m = 0; m < 4; ++m)
        #pragma unroll
        for (int n = 0; n < 4; ++n)
          acc[m][n] = __builtin_amdgcn_mfma_f32_16x16x32_bf16(a[m][ks], b[n], acc[m][n], 0, 0, 0);
    }

    // per-step running epilogue (C/D layout: col = li, row = lg*4 + reg)
    if (MODE == 0) {
      #pragma unroll
      for (int m = 0; m < 4; ++m)
        #pragma unroll
        for (int n = 0; n < 4; ++n)
          #pragma unroll
          for (int j = 0; j < 4; ++j)
            rs[m][j] += __expf(acc[m][n][j] * INV_T);
    } else {
      const int cbase = col0 + wc * 64 + li;
      #pragma unroll
      for (int m = 0; m < 4; ++m)
        #pragma unroll
        for (int j = 0; j < 4; ++j)
          #pragma unroll
          for (int n = 0; n < 4; ++n) {
            float v = acc[m][n][j];
            if (v > bv[m][j]) { bv[m][j] = v; bc[m][j] = cbase + n * 16; }  // strict >: first (smallest col) wins
          }
    }
    __syncthreads();  // drains vmcnt (prefetch landed) + all waves done reading cur
  }

  // ---- strip-end reduction + one atomic per row ----
  if (MODE == 0) {
    #pragma unroll
    for (int m = 0; m < 4; ++m)
      #pragma unroll
      for (int j = 0; j < 4; ++j) {
        float s = rs[m][j];
        #pragma unroll
        for (int msk = 1; msk < 16; msk <<= 1) s += __shfl_xor(s, msk, 64);
        if (li == 0) atomicAdd(&centsum[row0 + wr * 64 + m * 16 + lg * 4 + j], s);
      }
  } else {
    #pragma unroll
    for (int m = 0; m < 4; ++m)
      #pragma unroll
      for (int j = 0; j < 4; ++j) {
        float v = bv[m][j];
        int   c = bc[m][j];
        #pragma unroll
        for (int msk = 1; msk < 16; msk <<= 1) {
          float ov = __shfl_xor(v, msk, 64);
          int   oc = __shfl_xor(c, msk, 64);
          if (ov > v || (ov == v && oc < c)) { v = ov; c = oc; }
        }
        if (li == 0) atomicMax(&gpacked[row0 + wr * 64 + m * 16 + lg * 4 + j], packMax(v, c));
      }
  }
}

__global__ __launch_bounds__(256) void finalize_rows(const unsigned long long* __restrict__ gpacked,
                                                     const float* __restrict__ centsum,
                                                     float* __restrict__ jsum) {
  __shared__ float sdata[4];
  int b = blockIdx.x * 256 + threadIdx.x;
  unsigned long long pk = gpacked[b];
  unsigned int key = (unsigned int)(pk >> 32);
  unsigned int col = 0xFFFFFFFFu - (unsigned int)(pk & 0xFFFFFFFFu);
  unsigned int bits = (key & 0x80000000u) ? (key & 0x7FFFFFFFu) : ~key;
  float m = __uint_as_float(bits);
  float p = expf(m * INV_T);
  float J = logf(p) - logf(p + centsum[col]);  // BALANCE = 1.0
  #pragma unroll
  for (int msk = 1; msk < 64; msk <<= 1) J += __shfl_xor(J, msk, 64);
  int lane = threadIdx.x & 63, wv = threadIdx.x >> 6;
  if (lane == 0) sdata[wv] = J;
  __syncthreads();
  if (threadIdx.x == 0) atomicAdd(jsum, sdata[0] + sdata[1] + sdata[2] + sdata[3]);
}

__global__ void write_out(const float* __restrict__ jsum, float* __restrict__ out) {
  out[0] = -(jsum[0] / (float)B_ROWS);
}

extern "C" void kernel_launch(void* const* d_in, const int* in_sizes, int n_in,
                              void* d_out, int out_size, void* d_ws, size_t ws_size,
                              hipStream_t stream) {
  const float* features  = (const float*)d_in[0];
  const float* centroids = (const float*)d_in[1];
  float* out = (float*)d_out;

  // ws layout: cnorm_bf16[S*D] u16 | centsum[S] f32 | gpacked[B] u64 | jsum f32   (~3.5 MB)
  unsigned short* cbf = (unsigned short*)d_ws;
  float* centsum = (float*)(cbf + (size_t)S_ROWS * DIM);
  unsigned long long* gpacked = (unsigned long long*)(centsum + S_ROWS);
  float* jsum = (float*)(gpacked + B_ROWS);

  init_ws<<<dim3(64), dim3(256), 0, stream>>>(centsum, gpacked, jsum);
  normalize_centroids_bf16<<<dim3(S_ROWS / 4), dim3(256), 0, stream>>>(centroids, cbf);
  // MODE0: 100 row-blocks x 5 col-chunks (20 tiles each) = 500 blocks (~2/CU)
  strip_mfma<0><<<dim3(5, S_ROWS / 128), dim3(256), 0, stream>>>(nullptr, cbf, cbf, centsum, gpacked);
  // MODE1: 128 row-blocks x 4 col-chunks (25 tiles each) = 512 blocks (2/CU)
  strip_mfma<1><<<dim3(4, B_ROWS / 128), dim3(256), 0, stream>>>(features, nullptr, cbf, centsum, gpacked);
  finalize_rows<<<dim3(B_ROWS / 256), dim3(256), 0, stream>>>(gpacked, centsum, jsum);
  write_out<<<dim3(1), dim3(1), 0, stream>>>(jsum, out);
}